// Round 1
// baseline (100690.833 us; speedup 1.0000x reference)
//
#include <hip/hip_runtime.h>
#include <stdint.h>
#include <stddef.h>

typedef _Float16 f16;
typedef _Float16 half8 __attribute__((ext_vector_type(8)));
typedef float floatx4 __attribute__((ext_vector_type(4)));

#define MFMA(a,b,c) __builtin_amdgcn_mfma_f32_16x16x32_f16((a),(b),(c),0,0,0)

static constexpr int LMAX   = 1032;
static constexpr int TSTEPS = 1032;
static constexpr int RING   = 16;

// ---------------- ws layout (bytes) ----------------
static constexpr size_t ZBYTES    = (size_t)256*32*LMAX*2;          // fp16 z buffer
static constexpr size_t OFF_ZA    = 0;
static constexpr size_t OFF_ZB    = OFF_ZA + ZBYTES;
static constexpr size_t OFF_W1T   = OFF_ZB + ZBYTES;                // [2048][256] f16
static constexpr size_t OFF_W2T   = OFF_W1T + (size_t)2048*256*2;
static constexpr size_t OFF_UH1   = OFF_W2T + (size_t)2048*256*2;   // [128][512] f16
static constexpr size_t OFF_UI2   = OFF_UH1 + (size_t)128*512*2;
static constexpr size_t OFF_UH2   = OFF_UI2 + (size_t)128*512*2;
static constexpr size_t OFF_B1    = OFF_UH2 + (size_t)128*512*2;    // 2048 f32
static constexpr size_t OFF_B2    = OFF_B1 + (size_t)2048*4;
static constexpr size_t OFF_STATS = OFF_B2 + (size_t)2048*4;        // 4 blocks x 64 f32
static constexpr size_t OFF_AB    = OFF_STATS + (size_t)4*64*4;     // 4 blocks x 64 f32
static constexpr size_t OFF_RING  = OFF_AB + (size_t)4*64*4;        // 16 g x 16 slots x 16x512 f16
static constexpr size_t OFF_FLAGS = OFF_RING + (size_t)16*RING*16*512*2;
// total ~40.6 MB

__device__ __forceinline__ float sigm(float x){ return 1.f/(1.f+__expf(-x)); }
__device__ __forceinline__ float tanh_f(float x){ float e=__expf(2.f*x); return (e-1.f)/(e+1.f); }

// ---------------- zero flags/stats ----------------
__global__ void k_zero(float* stats, uint32_t* flags){
  int t = threadIdx.x;
  if (t < 256) stats[t] = 0.f;
  if (t < 512) flags[t] = 0u;
}

// ---------------- weight prep ----------------
// dst[n][k] (k=256) = k<128 ? Va[k][n] : Vb[k-128][n], Va/Vb are [128][2048] f32
__global__ void k_prep_V(f16* dst, const float* Va, const float* Vb){
  int idx = blockIdx.x*256 + threadIdx.x;
  if (idx < 2048*256){
    int n = idx >> 8, k = idx & 255;
    float v = (k < 128) ? Va[(size_t)k*2048 + n] : Vb[(size_t)(k-128)*2048 + n];
    dst[idx] = (f16)v;
  }
}
// dst[n][k] (n=128,k=512) = U[k][n], U is [512][128] f32
__global__ void k_prep_U(f16* dst, const float* U){
  int idx = blockIdx.x*256 + threadIdx.x;
  if (idx < 128*512){
    int n = idx >> 9, k = idx & 511;
    dst[idx] = (f16)U[(size_t)k*128 + n];
  }
}
__global__ void k_prep_bias(float* dst, const float* a, const float* b){
  int idx = blockIdx.x*256 + threadIdx.x;
  if (idx < 2048) dst[idx] = a[idx] + b[idx];
}

// ---------------- conv block: depthwise K=7 pad4 + pointwise + stats ----------------
// input: either x0 (block1: (256,1024,16) f32) or zin (f16, pre-BN) with abp = {a[32],b[32]}
__global__ __launch_bounds__(256) void k_conv(
    const float* __restrict__ x0, const f16* __restrict__ zin,
    const float* __restrict__ abp,
    const float* __restrict__ dwk, const float* __restrict__ dwb,
    const float* __restrict__ pwk, const float* __restrict__ pwb,
    f16* __restrict__ zout, float* __restrict__ stats,
    int Lin, int Cin)
{
  const int tid = threadIdx.x;
  const int b = blockIdx.y;
  const int l = blockIdx.x*256 + tid;
  const int Lout = Lin + 2;
  __shared__ float sPw[32*32], sDw[32*7], sDb[32], sPb[32], sAb[64];
  __shared__ float sRed[2][4][32];
  for (int i=tid; i<Cin*32; i+=256) sPw[i] = pwk[i];
  for (int i=tid; i<Cin*7;  i+=256) sDw[i] = dwk[i];
  if (tid < Cin) sDb[tid] = dwb[tid];
  if (tid >= 64 && tid < 96) sPb[tid-64] = pwb[tid-64];
  if (abp != nullptr && tid >= 128 && tid < 192) sAb[tid-128] = abp[tid-128];
  __syncthreads();

  float acc[32];
  #pragma unroll
  for (int o=0;o<32;++o) acc[o] = sPb[o];
  const bool act = (l < Lout);
  if (act){
    for (int c=0;c<Cin;++c){
      float s = sDb[c];
      #pragma unroll
      for (int k=0;k<7;++k){
        int li = l + k - 4;
        float v = 0.f;
        if (li >= 0 && li < Lin){
          if (x0) v = x0[((size_t)b*1024 + li)*16 + c];
          else {
            float z = (float)zin[((size_t)b*32 + c)*LMAX + li];
            v = fmaxf(sAb[c]*z + sAb[32+c], 0.f);
          }
        }
        s += sDw[c*7+k]*v;
      }
      #pragma unroll
      for (int o=0;o<32;++o) acc[o] += sPw[o*Cin + c]*s;
    }
    #pragma unroll
    for (int o=0;o<32;++o) zout[((size_t)b*32 + o)*LMAX + l] = (f16)acc[o];
  }
  // per-channel stats (sum, sumsq) reduced over the block, then atomics
  const int lane = tid & 63, wv = tid >> 6;
  for (int o=0;o<32;++o){
    float v = act ? acc[o] : 0.f;
    float q = v*v;
    #pragma unroll
    for (int m=1;m<64;m<<=1){ v += __shfl_xor(v,m); q += __shfl_xor(q,m); }
    if (lane == 0){ sRed[0][wv][o] = v; sRed[1][wv][o] = q; }
  }
  __syncthreads();
  if (tid < 32){
    float v = sRed[0][0][tid]+sRed[0][1][tid]+sRed[0][2][tid]+sRed[0][3][tid];
    float q = sRed[1][0][tid]+sRed[1][1][tid]+sRed[1][2][tid]+sRed[1][3][tid];
    atomicAdd(&stats[tid], v);
    atomicAdd(&stats[32+tid], q);
  }
}

__global__ void k_bnfin(const float* __restrict__ stats, const float* __restrict__ g,
                        const float* __restrict__ beta, float* __restrict__ ab, float inv_n)
{
  int o = threadIdx.x;
  if (o < 32){
    float m = stats[o]*inv_n;
    float var = stats[32+o]*inv_n - m*m;
    float a = g[o]*rsqrtf(var + 1e-5f);
    ab[o] = a; ab[32+o] = beta[o] - m*a;
  }
}

// ---------------- LSTM helpers ----------------
// tmp (16x32 per wave) = sIn(16x512 f16) @ UT^T ; UT is [128][512] (col-major weight)
__device__ __forceinline__ void mm_tmp(f16 sIn[16][520], const f16* __restrict__ UT,
                                       f16 sOut[16][264], int outbase,
                                       int w, int lm, int lq, int koff)
{
  floatx4 t0 = {0.f,0.f,0.f,0.f}, t1 = {0.f,0.f,0.f,0.f};
  const int c0 = 32*w + lm, c1 = c0 + 16;
  #pragma unroll
  for (int q=0;q<16;++q){
    half8 a = *(const half8*)&sIn[lm][q*32 + koff];
    t0 = MFMA(a, *(const half8*)&UT[(size_t)c0*512 + q*32 + koff], t0);
    t1 = MFMA(a, *(const half8*)&UT[(size_t)c1*512 + q*32 + koff], t1);
  }
  #pragma unroll
  for (int r=0;r<4;++r){
    sOut[lq*4+r][outbase + c0] = (f16)t0[r];
    sOut[lq*4+r][outbase + c1] = (f16)t1[r];
  }
}

// gates (wave w handles h-slice [128w,128w+128)) : sA(16x256) @ WT-slice + bias -> cell update -> h into sH
__device__ __forceinline__ void lstm_gates(f16 sAp[16][264], f16 sHp[16][520],
    const f16* __restrict__ WT, const float* __restrict__ bias,
    float* __restrict__ creg, int w, int lm, int lq, int koff)
{
  #pragma unroll
  for (int pass=0; pass<2; ++pass){
    floatx4 acc[4][4];
    const int cbase = 128*w + pass*64 + lm;
    #pragma unroll
    for (int s=0;s<4;++s)
      #pragma unroll
      for (int n=0;n<4;++n){
        float bv = bias[s*512 + cbase + 16*n];
        acc[s][n] = (floatx4){bv,bv,bv,bv};
      }
    #pragma unroll
    for (int q=0;q<8;++q){
      half8 a = *(const half8*)&sAp[lm][q*32 + koff];
      #pragma unroll
      for (int s=0;s<4;++s)
        #pragma unroll
        for (int n=0;n<4;++n){
          const f16* bp = &WT[(size_t)(s*512 + cbase + 16*n)*256 + q*32 + koff];
          acc[s][n] = MFMA(a, *(const half8*)bp, acc[s][n]);
        }
    }
    #pragma unroll
    for (int n=0;n<4;++n){
      const int hc = cbase + 16*n;
      #pragma unroll
      for (int r=0;r<4;++r){
        float* cr = &creg[pass*16 + n*4 + r];
        float iv = sigm(acc[0][n][r]);
        float fv = sigm(acc[1][n][r]);
        float gv = tanh_f(acc[2][n][r]);
        float ov = sigm(acc[3][n][r]);
        float c = fv*(*cr) + iv*gv;
        *cr = c;
        sHp[lq*4+r][hc] = (f16)(ov*tanh_f(c));
      }
    }
  }
}

// ---------------- persistent 2-layer LSTM, 16 groups x {producer,consumer} ----------------
__global__ __launch_bounds__(256,1) void k_lstm(
  const f16* __restrict__ z4, const float* __restrict__ ab4, const float* __restrict__ Ui1,
  const f16* __restrict__ W1T, const f16* __restrict__ Uh1T, const float* __restrict__ bias1,
  const f16* __restrict__ W2T, const f16* __restrict__ Ui2T, const f16* __restrict__ Uh2T,
  const float* __restrict__ bias2,
  const float* __restrict__ fcw, const float* __restrict__ fcb,
  uint32_t* __restrict__ ringu, uint32_t* __restrict__ prodf, uint32_t* __restrict__ consf,
  float* __restrict__ outp)
{
  const int tid  = threadIdx.x;
  const int lane = tid & 63;
  const int w    = tid >> 6;
  const int g    = blockIdx.x >> 1;
  const int role = blockIdx.x & 1;
  const int lm   = lane & 15;
  const int lq   = lane >> 4;
  const int koff = lq*8;

  __shared__ f16 sA [16][264];   // A operand: [x~|tmp1h] or [tmp2i|tmp2h]
  __shared__ f16 sH [16][520];   // h1 (role0) / h2 (role1)
  __shared__ f16 sHc[16][520];   // role1: staged h1
  __shared__ float sY[16][32];   // role0: BN'd conv4 column

  for (int i=tid; i<16*520; i+=256){ sH[i/520][i%520] = (f16)0.f; sHc[i/520][i%520] = (f16)0.f; }
  __syncthreads();

  if (role == 0){
    // ---------------- layer-1 producer ----------------
    float creg[32];
    #pragma unroll
    for (int i=0;i<32;++i) creg[i]=0.f;
    #pragma unroll 1
    for (int t=0;t<TSTEPS;++t){
      if (t >= RING){
        if (tid == 0){
          while ((int)__hip_atomic_load(&consf[g*16], __ATOMIC_RELAXED, __HIP_MEMORY_SCOPE_AGENT) < t-RING+1)
            __builtin_amdgcn_s_sleep(2);
        }
        __syncthreads();
      }
      // y4 = relu(bn(z4[:, :, t]))
      {
        int e = tid;
        #pragma unroll
        for (int j=0;j<2;++j,e+=256){
          int row = e >> 5, c = e & 31;
          float z = (float)z4[((size_t)(g*16+row)*32 + c)*LMAX + t];
          sY[row][c] = fmaxf(ab4[c]*z + ab4[32+c], 0.f);
        }
      }
      __syncthreads();
      // x~ = y4 @ Ui1  -> sA[:,0:128]
      {
        int row = tid >> 4, r0 = (tid & 15)*8;
        float a8[8] = {0,0,0,0,0,0,0,0};
        for (int c=0;c<32;++c){
          float y = sY[row][c];
          const float* u = &Ui1[(size_t)c*128 + r0];
          #pragma unroll
          for (int j=0;j<8;++j) a8[j] += y*u[j];
        }
        #pragma unroll
        for (int j=0;j<8;++j) sA[row][r0+j] = (f16)a8[j];
      }
      // tmp1h = h1 @ Uh1 -> sA[:,128:256]
      mm_tmp(sH, Uh1T, sA, 128, w, lm, lq, koff);
      __syncthreads();
      // gates1 -> c1,h1
      lstm_gates(sA, sH, W1T, bias1, creg, w, lm, lq, koff);
      __syncthreads();
      // publish h1 to ring (device-scope atomics; no fences -> no cache invalidation)
      uint32_t* slot = &ringu[((size_t)g*RING + (t & (RING-1)))*4096];
      #pragma unroll
      for (int j=0;j<16;++j){
        int d = tid + 256*j;
        int e = d*2, row = e >> 9, col = e & 511;
        uint32_t v = *(const uint32_t*)&sH[row][col];
        __hip_atomic_store(&slot[d], v, __ATOMIC_RELAXED, __HIP_MEMORY_SCOPE_AGENT);
      }
      asm volatile("s_waitcnt vmcnt(0)" ::: "memory");
      __syncthreads();
      if (tid == 0)
        __hip_atomic_store(&prodf[g*16], (uint32_t)(t+1), __ATOMIC_RELAXED, __HIP_MEMORY_SCOPE_AGENT);
    }
  } else {
    // ---------------- layer-2 consumer ----------------
    float creg[32];
    #pragma unroll
    for (int i=0;i<32;++i) creg[i]=0.f;
    #pragma unroll 1
    for (int t=0;t<TSTEPS;++t){
      if (tid == 0){
        while ((int)__hip_atomic_load(&prodf[g*16], __ATOMIC_RELAXED, __HIP_MEMORY_SCOPE_AGENT) < t+1)
          __builtin_amdgcn_s_sleep(2);
      }
      __syncthreads();
      const uint32_t* slot = &ringu[((size_t)g*RING + (t & (RING-1)))*4096];
      #pragma unroll
      for (int j=0;j<16;++j){
        int d = tid + 256*j;
        uint32_t v = __hip_atomic_load(&slot[d], __ATOMIC_RELAXED, __HIP_MEMORY_SCOPE_AGENT);
        int e = d*2, row = e >> 9, col = e & 511;
        *(uint32_t*)&sHc[row][col] = v;
      }
      asm volatile("s_waitcnt vmcnt(0)" ::: "memory");
      __syncthreads();
      if (tid == 0)
        __hip_atomic_store(&consf[g*16], (uint32_t)(t+1), __ATOMIC_RELAXED, __HIP_MEMORY_SCOPE_AGENT);
      // tmp2i = h1 @ Ui2 -> sA[:,0:128] ; tmp2h = h2 @ Uh2 -> sA[:,128:256]
      mm_tmp(sHc, Ui2T, sA, 0,   w, lm, lq, koff);
      mm_tmp(sH,  Uh2T, sA, 128, w, lm, lq, koff);
      __syncthreads();
      // gates2 -> c2,h2
      lstm_gates(sA, sH, W2T, bias2, creg, w, lm, lq, koff);
      __syncthreads();
    }
    // final: out = h2 @ fc_w^T + fc_b
    if (tid < 160){
      int row = tid/10, nc = tid%10;
      float s = fcb[nc];
      const float* wv = &fcw[(size_t)nc*512];
      for (int k=0;k<512;++k) s += (float)sH[row][k]*wv[k];
      outp[(size_t)(g*16+row)*10 + nc] = s;
    }
  }
}

// ---------------- host ----------------
extern "C" void kernel_launch(void* const* d_in, const int* in_sizes, int n_in,
                              void* d_out, int out_size, void* d_ws, size_t ws_size,
                              hipStream_t stream)
{
  (void)in_sizes; (void)n_in; (void)out_size; (void)ws_size;
  const float* x = (const float*)d_in[0];
  auto F = [&](int i){ return (const float*)d_in[i]; };
  // conv blocks i=1..4 at base 1+6*(i-1): dw_k, dw_b, pw_k, pw_b, bn_g, bn_b
  const float *Ui1=F(25), *Vi1=F(26), *Uh1=F(27), *Vh1=F(28), *bi1=F(29), *bh1=F(30);
  const float *Ui2=F(31), *Vi2=F(32), *Uh2=F(33), *Vh2=F(34), *bi2=F(35), *bh2=F(36);
  const float *fcw=F(37), *fcb=F(38);

  uint8_t* ws = (uint8_t*)d_ws;
  f16* zA   = (f16*)(ws + OFF_ZA);
  f16* zB   = (f16*)(ws + OFF_ZB);
  f16* W1T  = (f16*)(ws + OFF_W1T);
  f16* W2T  = (f16*)(ws + OFF_W2T);
  f16* Uh1T = (f16*)(ws + OFF_UH1);
  f16* Ui2T = (f16*)(ws + OFF_UI2);
  f16* Uh2T = (f16*)(ws + OFF_UH2);
  float* bias1 = (float*)(ws + OFF_B1);
  float* bias2 = (float*)(ws + OFF_B2);
  float* stats = (float*)(ws + OFF_STATS);
  float* ab    = (float*)(ws + OFF_AB);
  uint32_t* ringu = (uint32_t*)(ws + OFF_RING);
  uint32_t* prodf = (uint32_t*)(ws + OFF_FLAGS);
  uint32_t* consf = prodf + 256;
  float* outp = (float*)d_out;

  k_zero<<<1, 512, 0, stream>>>(stats, prodf);

  k_prep_V<<<2048, 256, 0, stream>>>(W1T, Vi1, Vh1);
  k_prep_V<<<2048, 256, 0, stream>>>(W2T, Vi2, Vh2);
  k_prep_U<<<256, 256, 0, stream>>>(Uh1T, Uh1);
  k_prep_U<<<256, 256, 0, stream>>>(Ui2T, Ui2);
  k_prep_U<<<256, 256, 0, stream>>>(Uh2T, Uh2);
  k_prep_bias<<<8, 256, 0, stream>>>(bias1, bi1, bh1);
  k_prep_bias<<<8, 256, 0, stream>>>(bias2, bi2, bh2);

  dim3 cgrid(5, 256);
  // block 1: x -> zA (Lin=1024, Cin=16)
  k_conv<<<cgrid, 256, 0, stream>>>(x, nullptr, nullptr, F(1), F(2), F(3), F(4),
                                    zA, stats + 0*64, 1024, 16);
  k_bnfin<<<1, 64, 0, stream>>>(stats + 0*64, F(5), F(6), ab + 0*64, 1.f/(256.f*1026.f));
  // block 2: zA -> zB (Lin=1026, Cin=32)
  k_conv<<<cgrid, 256, 0, stream>>>(nullptr, zA, ab + 0*64, F(7), F(8), F(9), F(10),
                                    zB, stats + 1*64, 1026, 32);
  k_bnfin<<<1, 64, 0, stream>>>(stats + 1*64, F(11), F(12), ab + 1*64, 1.f/(256.f*1028.f));
  // block 3: zB -> zA (Lin=1028)
  k_conv<<<cgrid, 256, 0, stream>>>(nullptr, zB, ab + 1*64, F(13), F(14), F(15), F(16),
                                    zA, stats + 2*64, 1028, 32);
  k_bnfin<<<1, 64, 0, stream>>>(stats + 2*64, F(17), F(18), ab + 2*64, 1.f/(256.f*1030.f));
  // block 4: zA -> zB (Lin=1030)
  k_conv<<<cgrid, 256, 0, stream>>>(nullptr, zA, ab + 2*64, F(19), F(20), F(21), F(22),
                                    zB, stats + 3*64, 1030, 32);
  k_bnfin<<<1, 64, 0, stream>>>(stats + 3*64, F(23), F(24), ab + 3*64, 1.f/(256.f*1032.f));

  k_lstm<<<32, 256, 0, stream>>>(zB, ab + 3*64, Ui1,
                                 W1T, Uh1T, bias1,
                                 W2T, Ui2T, Uh2T, bias2,
                                 fcw, fcb,
                                 ringu, prodf, consf, outp);
}

// Round 2
// 7878.195 us; speedup vs baseline: 12.7810x; 12.7810x over previous
//
#include <hip/hip_runtime.h>
#include <stdint.h>
#include <stddef.h>

typedef _Float16 f16;
typedef _Float16 half8 __attribute__((ext_vector_type(8)));
typedef float floatx4 __attribute__((ext_vector_type(4)));

#define MFMA(a,b,c) __builtin_amdgcn_mfma_f32_16x16x32_f16((a),(b),(c),0,0,0)

static constexpr int LMAX   = 1032;
static constexpr int TSTEPS = 1032;

// ---------------- ws layout (bytes) ----------------
static constexpr size_t ZBYTES    = (size_t)256*32*LMAX*2;          // fp16 z buffer
static constexpr size_t OFF_ZA    = 0;
static constexpr size_t OFF_ZB    = OFF_ZA + ZBYTES;
static constexpr size_t OFF_W1F   = OFF_ZB + ZBYTES;                // frag-ordered [8b][16tile][8q][64lane][8] f16
static constexpr size_t OFF_W2F   = OFF_W1F + (size_t)524288*2;
static constexpr size_t OFF_UH1F  = OFF_W2F + (size_t)524288*2;     // [8b][16q][64][8] f16
static constexpr size_t OFF_UI2F  = OFF_UH1F + (size_t)65536*2;
static constexpr size_t OFF_UH2F  = OFF_UI2F + (size_t)65536*2;
static constexpr size_t OFF_UI1F  = OFF_UH2F + (size_t)65536*2;     // [8b][64][8] f16
static constexpr size_t OFF_B1    = OFF_UI1F + (size_t)4096*2;      // 2048 f32
static constexpr size_t OFF_B2    = OFF_B1 + (size_t)2048*4;
static constexpr size_t OFF_STATS = OFF_B2 + (size_t)2048*4;        // 4 conv blocks x 64 f32
static constexpr size_t OFF_AB    = OFF_STATS + (size_t)4*64*4;
static constexpr size_t OFF_H1X   = OFF_AB + (size_t)4*64*4;        // [16g][4slot][16][512] f16
static constexpr size_t OFF_H2X   = OFF_H1X + (size_t)16*4*16*512*2;// [16g][2slot][16][512] f16
static constexpr size_t OFF_AX    = OFF_H2X + (size_t)16*2*16*512*2;// [16g][2role][2slot][16][256] f16
static constexpr size_t OFF_FLAGS = OFF_AX + (size_t)16*2*2*16*256*2; // [16g][4type][8b] u32
// total ~37.2 MB

__device__ __forceinline__ float sigm(float x){ return 1.f/(1.f+__expf(-x)); }
__device__ __forceinline__ float tanh_f(float x){ float e=__expf(2.f*x); return (e-1.f)/(e+1.f); }

__device__ __forceinline__ half8 ldA16(const f16* p){
  const uint64_t* q = (const uint64_t*)p;
  uint64_t a = __hip_atomic_load(q,   __ATOMIC_RELAXED, __HIP_MEMORY_SCOPE_AGENT);
  uint64_t b = __hip_atomic_load(q+1, __ATOMIC_RELAXED, __HIP_MEMORY_SCOPE_AGENT);
  union { uint64_t u[2]; half8 h; } x; x.u[0]=a; x.u[1]=b; return x.h;
}
__device__ __forceinline__ void st8(f16* p, uint64_t v){
  __hip_atomic_store((uint64_t*)p, v, __ATOMIC_RELAXED, __HIP_MEMORY_SCOPE_AGENT);
}

// ---------------- zero flags/stats ----------------
__global__ void k_zero(float* stats, uint32_t* flags){
  int t = threadIdx.x;
  if (t < 256) stats[t] = 0.f;
  if (t < 512) flags[t] = 0u;
}

// ---------------- weight prep (fragment layouts) ----------------
// W frags: flat = (((b*16 + tile)*8 + q)*64 + lane)*8 + j ; tile = s*4+w
// value = k<128 ? Vi[k][col] : Vh[k-128][col], col = s*512 + b*64 + w*16 + (lane&15), k = q*32+(lane>>4)*8+j
__global__ void k_prep_Wfrag(f16* dst, const float* Vi, const float* Vh){
  int f = blockIdx.x*256 + threadIdx.x;
  if (f < 524288){
    int j = f & 7, lane = (f>>3)&63, q = (f>>9)&7, tile = (f>>12)&15, b = f>>16;
    int s = tile>>2, w = tile&3;
    int k = q*32 + (lane>>4)*8 + j;
    int col = s*512 + b*64 + w*16 + (lane&15);
    float v = (k < 128) ? Vi[(size_t)k*2048 + col] : Vh[(size_t)(k-128)*2048 + col];
    dst[f] = (f16)v;
  }
}
// U frags (k=512): flat = ((b*16+q)*64+lane)*8+j ; value = U[k][b*16+(lane&15)]
__global__ void k_prep_Ufrag(f16* dst, const float* U){
  int f = blockIdx.x*256 + threadIdx.x;
  if (f < 65536){
    int j = f & 7, lane = (f>>3)&63, q = (f>>9)&15, b = f>>13;
    int k = q*32 + (lane>>4)*8 + j;
    int col = b*16 + (lane&15);
    dst[f] = (f16)U[(size_t)k*128 + col];
  }
}
// Ui1 frags (k=32): flat = (b*64+lane)*8+j
__global__ void k_prep_Ui1frag(f16* dst, const float* U){
  int f = blockIdx.x*256 + threadIdx.x;
  if (f < 4096){
    int j = f & 7, lane = (f>>3)&63, b = f>>9;
    int k = (lane>>4)*8 + j;
    int col = b*16 + (lane&15);
    dst[f] = (f16)U[(size_t)k*128 + col];
  }
}
__global__ void k_prep_bias(float* dst, const float* a, const float* b){
  int idx = blockIdx.x*256 + threadIdx.x;
  if (idx < 2048) dst[idx] = a[idx] + b[idx];
}

// ---------------- conv block (unchanged from R1, verified) ----------------
__global__ __launch_bounds__(256) void k_conv(
    const float* __restrict__ x0, const f16* __restrict__ zin,
    const float* __restrict__ abp,
    const float* __restrict__ dwk, const float* __restrict__ dwb,
    const float* __restrict__ pwk, const float* __restrict__ pwb,
    f16* __restrict__ zout, float* __restrict__ stats,
    int Lin, int Cin)
{
  const int tid = threadIdx.x;
  const int b = blockIdx.y;
  const int l = blockIdx.x*256 + tid;
  const int Lout = Lin + 2;
  __shared__ float sPw[32*32], sDw[32*7], sDb[32], sPb[32], sAb[64];
  __shared__ float sRed[2][4][32];
  for (int i=tid; i<Cin*32; i+=256) sPw[i] = pwk[i];
  for (int i=tid; i<Cin*7;  i+=256) sDw[i] = dwk[i];
  if (tid < Cin) sDb[tid] = dwb[tid];
  if (tid >= 64 && tid < 96) sPb[tid-64] = pwb[tid-64];
  if (abp != nullptr && tid >= 128 && tid < 192) sAb[tid-128] = abp[tid-128];
  __syncthreads();

  float acc[32];
  #pragma unroll
  for (int o=0;o<32;++o) acc[o] = sPb[o];
  const bool act = (l < Lout);
  if (act){
    for (int c=0;c<Cin;++c){
      float s = sDb[c];
      #pragma unroll
      for (int k=0;k<7;++k){
        int li = l + k - 4;
        float v = 0.f;
        if (li >= 0 && li < Lin){
          if (x0) v = x0[((size_t)b*1024 + li)*16 + c];
          else {
            float z = (float)zin[((size_t)b*32 + c)*LMAX + li];
            v = fmaxf(sAb[c]*z + sAb[32+c], 0.f);
          }
        }
        s += sDw[c*7+k]*v;
      }
      #pragma unroll
      for (int o=0;o<32;++o) acc[o] += sPw[o*Cin + c]*s;
    }
    #pragma unroll
    for (int o=0;o<32;++o) zout[((size_t)b*32 + o)*LMAX + l] = (f16)acc[o];
  }
  const int lane = tid & 63, wv = tid >> 6;
  for (int o=0;o<32;++o){
    float v = act ? acc[o] : 0.f;
    float q = v*v;
    #pragma unroll
    for (int m=1;m<64;m<<=1){ v += __shfl_xor(v,m); q += __shfl_xor(q,m); }
    if (lane == 0){ sRed[0][wv][o] = v; sRed[1][wv][o] = q; }
  }
  __syncthreads();
  if (tid < 32){
    float v = sRed[0][0][tid]+sRed[0][1][tid]+sRed[0][2][tid]+sRed[0][3][tid];
    float q = sRed[1][0][tid]+sRed[1][1][tid]+sRed[1][2][tid]+sRed[1][3][tid];
    atomicAdd(&stats[tid], v);
    atomicAdd(&stats[32+tid], q);
  }
}

__global__ void k_bnfin(const float* __restrict__ stats, const float* __restrict__ g,
                        const float* __restrict__ beta, float* __restrict__ ab, float inv_n)
{
  int o = threadIdx.x;
  if (o < 32){
    float m = stats[o]*inv_n;
    float var = stats[32+o]*inv_n - m*m;
    float a = g[o]*rsqrtf(var + 1e-5f);
    ab[o] = a; ab[32+o] = beta[o] - m*a;
  }
}

// ---------------- persistent 2-layer LSTM: 16 groups x 2 roles x 8 col-split blocks ----------------
// Flags: type 0 = FH1 (producer step done), 1 = FH2 (consumer step done),
//        2 = FA0 (producer tmp published),  3 = FA1 (consumer tmp published)
__global__ __launch_bounds__(256,1) void k_lstm(
  const f16* __restrict__ z4, const float* __restrict__ ab4,
  const f16* __restrict__ W1F, const f16* __restrict__ W2F,
  const f16* __restrict__ Uh1F, const f16* __restrict__ Ui1F,
  const f16* __restrict__ Ui2F, const f16* __restrict__ Uh2F,
  const float* __restrict__ bias1, const float* __restrict__ bias2,
  f16* __restrict__ h1x, f16* __restrict__ h2x, f16* __restrict__ Ax,
  uint32_t* __restrict__ flags,
  const float* __restrict__ fcw, const float* __restrict__ fcb,
  float* __restrict__ outp)
{
  const int tid  = threadIdx.x;
  const int lane = tid & 63;
  const int w    = tid >> 6;
  const int lm   = lane & 15;
  const int lq   = lane >> 4;
  const int lq8  = lq*8;
  const int lq4  = lq*4;
  // XCD swizzle: all 16 blocks of a group land on one XCD (perf hint only)
  const int x  = blockIdx.x & 7;
  const int s_ = blockIdx.x >> 3;          // 0..31
  const int g  = x + ((s_ >= 16) ? 8 : 0);
  const int rb = s_ & 15;
  const int role = rb >> 3;
  const int b    = rb & 7;

  __shared__ __align__(16) f16 sUB[2][16][64][8];  // B-frags for tmp tiles (32 KB)
  __shared__ __align__(16) f16 sY[64][8];          // y4 A-frag (k=32)
  __shared__ __align__(16) f16 sTmp[16][32];       // staged tmp slice (C-layout)
  __shared__ __align__(16) f16 sHs[16][64];        // staged h slice

  // ---- load LDS B-frags for tmp (once) ----
  {
    const f16* UhF = role ? Uh2F : Uh1F;
    const uint4* src1 = (const uint4*)(UhF + (size_t)b*16*64*8);
    uint4* d1 = (uint4*)&sUB[1][0][0][0];
    for (int i=tid;i<1024;i+=256) d1[i] = src1[i];
    uint4* d0 = (uint4*)&sUB[0][0][0][0];
    if (role == 0){
      const uint4* s0 = (const uint4*)(Ui1F + (size_t)b*64*8);
      if (tid < 64) d0[tid] = s0[tid];
    } else {
      const uint4* s0 = (const uint4*)(Ui2F + (size_t)b*16*64*8);
      for (int i=tid;i<1024;i+=256) d0[i] = s0[i];
    }
  }
  // ---- load W slice B-frags into VGPRs (once): wave w holds 4 gate-tiles x 8 q ----
  half8 wf[4][8];
  {
    const f16* WB = (role ? W2F : W1F) + (size_t)b*16*8*64*8;
    #pragma unroll
    for (int s=0;s<4;++s)
      #pragma unroll
      for (int q=0;q<8;++q)
        wf[s][q] = *(const half8*)&WB[ (((size_t)(s*4+w)*8 + q)*64 + lane)*8 ];
  }
  // ---- bias for this lane's gate columns ----
  float bs[4];
  {
    const float* bias = role ? bias2 : bias1;
    #pragma unroll
    for (int s=0;s<4;++s) bs[s] = bias[s*512 + b*64 + w*16 + lm];
  }
  __syncthreads();

  uint32_t* FH1 = &flags[(g*4+0)*8];
  uint32_t* FH2 = &flags[(g*4+1)*8];
  uint32_t* FA0 = &flags[(g*4+2)*8];
  uint32_t* FA1 = &flags[(g*4+3)*8];

  float creg[4] = {0.f,0.f,0.f,0.f};

  #pragma unroll 1
  for (int t=0; t<TSTEPS; ++t){
    // ---------- phase 1: wait for step inputs ----------
    if (role == 0){
      if (t > 0 && tid < 8){
        while (__hip_atomic_load(&FH1[tid], __ATOMIC_RELAXED, __HIP_MEMORY_SCOPE_AGENT) < (uint32_t)t)
          __builtin_amdgcn_s_sleep(1);
      }
    } else {
      if (tid < 8){
        while (__hip_atomic_load(&FH1[tid], __ATOMIC_RELAXED, __HIP_MEMORY_SCOPE_AGENT) < (uint32_t)(t+1))
          __builtin_amdgcn_s_sleep(1);
      }
      if (t > 0 && tid >= 8 && tid < 16){
        while (__hip_atomic_load(&FH2[tid-8], __ATOMIC_RELAXED, __HIP_MEMORY_SCOPE_AGENT) < (uint32_t)t)
          __builtin_amdgcn_s_sleep(1);
      }
    }
    __syncthreads();

    // producer: build y4 A-frag for this t
    if (role == 0){
      int e = tid;
      #pragma unroll
      for (int jj=0;jj<2;++jj,e+=256){
        int row = e>>5, c = e&31;
        float z = (float)z4[((size_t)(g*16+row)*32 + c)*LMAX + t];
        float v = fmaxf(ab4[c]*z + ab4[32+c], 0.f);
        sY[row + 16*(c>>3)][c&7] = (f16)v;
      }
      __syncthreads();
    }

    // ---------- phase 2: tmp tiles (waves 0,1) ----------
    if (w < 2){
      floatx4 tc = {0.f,0.f,0.f,0.f};
      if (role == 0){
        if (w == 0){
          half8 ay = *(const half8*)&sY[lane][0];
          half8 bu = *(const half8*)&sUB[0][0][lane][0];
          tc = MFMA(ay, bu, tc);
        } else if (t > 0){
          const f16* H = h1x + ((size_t)(g*4 + ((t-1)&3))*16)*512;
          #pragma unroll
          for (int q=0;q<16;++q){
            half8 a = ldA16(H + lm*512 + q*32 + lq8);
            half8 bu = *(const half8*)&sUB[1][q][lane][0];
            tc = MFMA(a, bu, tc);
          }
        }
      } else {
        if (w == 0 || t > 0){
          const f16* H = (w==0) ? h1x + ((size_t)(g*4 + (t&3))*16)*512
                                : h2x + ((size_t)(g*2 + ((t-1)&1))*16)*512;
          #pragma unroll
          for (int q=0;q<16;++q){
            half8 a = ldA16(H + lm*512 + q*32 + lq8);
            half8 bu = (w==0) ? *(const half8*)&sUB[0][q][lane][0]
                              : *(const half8*)&sUB[1][q][lane][0];
            tc = MFMA(a, bu, tc);
          }
        }
      }
      #pragma unroll
      for (int r=0;r<4;++r) sTmp[lq4+r][w*16 + lm] = (f16)tc[r];
    }
    __syncthreads();

    // ---------- phase 3: publish tmp slice (1 KB) ----------
    {
      f16* AxS = Ax + ((size_t)((g*2+role)*2 + (t&1))*16)*256;
      if (tid < 128){
        int row = tid>>3, cc = (tid&7)*4;
        uint64_t v = *(const uint64_t*)&sTmp[row][cc];
        int col = (cc < 16) ? (b*16 + cc) : (128 + b*16 + (cc-16));
        st8(AxS + row*256 + col, v);
      }
      asm volatile("s_waitcnt vmcnt(0)" ::: "memory");
      __syncthreads();
      if (tid == 0){
        uint32_t* FA = role ? FA1 : FA0;
        __hip_atomic_store(&FA[b], (uint32_t)(t+1), __ATOMIC_RELAXED, __HIP_MEMORY_SCOPE_AGENT);
      }
    }
    // ---------- phase 4: wait all tmp slices ----------
    if (tid < 8){
      uint32_t* FA = role ? FA1 : FA0;
      while (__hip_atomic_load(&FA[tid], __ATOMIC_RELAXED, __HIP_MEMORY_SCOPE_AGENT) < (uint32_t)(t+1))
        __builtin_amdgcn_s_sleep(1);
    }
    __syncthreads();

    // ---------- phase 5: gates MM (all waves) + cell update ----------
    {
      const f16* Abase = Ax + ((size_t)((g*2+role)*2 + (t&1))*16)*256;
      half8 afr[8];
      #pragma unroll
      for (int q=0;q<8;++q) afr[q] = ldA16(Abase + lm*256 + q*32 + lq8);
      floatx4 acc[4];
      #pragma unroll
      for (int s=0;s<4;++s){
        acc[s] = (floatx4){bs[s],bs[s],bs[s],bs[s]};
        #pragma unroll
        for (int q=0;q<8;++q) acc[s] = MFMA(afr[q], wf[s][q], acc[s]);
      }
      #pragma unroll
      for (int r=0;r<4;++r){
        float iv = sigm(acc[0][r]);
        float fv = sigm(acc[1][r]);
        float gv = tanh_f(acc[2][r]);
        float ov = sigm(acc[3][r]);
        float c = fv*creg[r] + iv*gv;
        creg[r] = c;
        sHs[lq4+r][w*16 + lm] = (f16)(ov*tanh_f(c));
      }
    }
    // producer: don't overwrite h1(t-4) until consumers are past it
    if (role == 0 && t >= 4 && tid < 8){
      while (__hip_atomic_load(&FH2[tid], __ATOMIC_RELAXED, __HIP_MEMORY_SCOPE_AGENT) < (uint32_t)(t-3))
        __builtin_amdgcn_s_sleep(1);
    }
    __syncthreads();

    // ---------- phase 6: publish h slice (2 KB) + step flag ----------
    {
      f16* Hd = (role == 0) ? h1x + ((size_t)(g*4 + (t&3))*16)*512
                            : h2x + ((size_t)(g*2 + (t&1))*16)*512;
      int row = tid>>4, cc = (tid&15)*4;
      uint64_t v = *(const uint64_t*)&sHs[row][cc];
      st8(Hd + row*512 + b*64 + cc, v);
      asm volatile("s_waitcnt vmcnt(0)" ::: "memory");
      __syncthreads();
      if (tid == 0){
        uint32_t* FH = role ? FH2 : FH1;
        __hip_atomic_store(&FH[b], (uint32_t)(t+1), __ATOMIC_RELAXED, __HIP_MEMORY_SCOPE_AGENT);
      }
    }
  }

  // ---------- epilogue: out = h2(T-1) @ fc_w^T + fc_b ----------
  if (role == 1 && b == 0){
    if (tid < 8){
      while (__hip_atomic_load(&FH2[tid], __ATOMIC_RELAXED, __HIP_MEMORY_SCOPE_AGENT) < (uint32_t)TSTEPS)
        __builtin_amdgcn_s_sleep(1);
    }
    __syncthreads();
    if (tid < 160){
      int row = tid/10, nc = tid%10;
      const f16* hrow = h2x + ((size_t)(g*2 + ((TSTEPS-1)&1))*16 + row)*512;
      float sum = fcb[nc];
      for (int k4=0;k4<128;++k4){
        uint64_t u = __hip_atomic_load((const uint64_t*)(hrow + k4*4), __ATOMIC_RELAXED, __HIP_MEMORY_SCOPE_AGENT);
        union { uint64_t uu; f16 h[4]; } cv; cv.uu = u;
        const float* wv = &fcw[(size_t)nc*512 + k4*4];
        #pragma unroll
        for (int i=0;i<4;++i) sum += (float)cv.h[i]*wv[i];
      }
      outp[(size_t)(g*16+row)*10 + nc] = sum;
    }
  }
}

// ---------------- host ----------------
extern "C" void kernel_launch(void* const* d_in, const int* in_sizes, int n_in,
                              void* d_out, int out_size, void* d_ws, size_t ws_size,
                              hipStream_t stream)
{
  (void)in_sizes; (void)n_in; (void)out_size; (void)ws_size;
  const float* x = (const float*)d_in[0];
  auto F = [&](int i){ return (const float*)d_in[i]; };
  const float *Ui1=F(25), *Vi1=F(26), *Uh1=F(27), *Vh1=F(28), *bi1=F(29), *bh1=F(30);
  const float *Ui2=F(31), *Vi2=F(32), *Uh2=F(33), *Vh2=F(34), *bi2=F(35), *bh2=F(36);
  const float *fcw=F(37), *fcb=F(38);

  uint8_t* ws = (uint8_t*)d_ws;
  f16* zA   = (f16*)(ws + OFF_ZA);
  f16* zB   = (f16*)(ws + OFF_ZB);
  f16* W1F  = (f16*)(ws + OFF_W1F);
  f16* W2F  = (f16*)(ws + OFF_W2F);
  f16* Uh1F = (f16*)(ws + OFF_UH1F);
  f16* Ui2F = (f16*)(ws + OFF_UI2F);
  f16* Uh2F = (f16*)(ws + OFF_UH2F);
  f16* Ui1F = (f16*)(ws + OFF_UI1F);
  float* bias1 = (float*)(ws + OFF_B1);
  float* bias2 = (float*)(ws + OFF_B2);
  float* stats = (float*)(ws + OFF_STATS);
  float* ab    = (float*)(ws + OFF_AB);
  f16* h1x  = (f16*)(ws + OFF_H1X);
  f16* h2x  = (f16*)(ws + OFF_H2X);
  f16* Axb  = (f16*)(ws + OFF_AX);
  uint32_t* flags = (uint32_t*)(ws + OFF_FLAGS);
  float* outp = (float*)d_out;

  k_zero<<<1, 512, 0, stream>>>(stats, flags);

  k_prep_Wfrag<<<2048, 256, 0, stream>>>(W1F, Vi1, Vh1);
  k_prep_Wfrag<<<2048, 256, 0, stream>>>(W2F, Vi2, Vh2);
  k_prep_Ufrag<<<256, 256, 0, stream>>>(Uh1F, Uh1);
  k_prep_Ufrag<<<256, 256, 0, stream>>>(Ui2F, Ui2);
  k_prep_Ufrag<<<256, 256, 0, stream>>>(Uh2F, Uh2);
  k_prep_Ui1frag<<<16, 256, 0, stream>>>(Ui1F, Ui1);
  k_prep_bias<<<8, 256, 0, stream>>>(bias1, bi1, bh1);
  k_prep_bias<<<8, 256, 0, stream>>>(bias2, bi2, bh2);

  dim3 cgrid(5, 256);
  k_conv<<<cgrid, 256, 0, stream>>>(x, nullptr, nullptr, F(1), F(2), F(3), F(4),
                                    zA, stats + 0*64, 1024, 16);
  k_bnfin<<<1, 64, 0, stream>>>(stats + 0*64, F(5), F(6), ab + 0*64, 1.f/(256.f*1026.f));
  k_conv<<<cgrid, 256, 0, stream>>>(nullptr, zA, ab + 0*64, F(7), F(8), F(9), F(10),
                                    zB, stats + 1*64, 1026, 32);
  k_bnfin<<<1, 64, 0, stream>>>(stats + 1*64, F(11), F(12), ab + 1*64, 1.f/(256.f*1028.f));
  k_conv<<<cgrid, 256, 0, stream>>>(nullptr, zB, ab + 1*64, F(13), F(14), F(15), F(16),
                                    zA, stats + 2*64, 1028, 32);
  k_bnfin<<<1, 64, 0, stream>>>(stats + 2*64, F(17), F(18), ab + 2*64, 1.f/(256.f*1030.f));
  k_conv<<<cgrid, 256, 0, stream>>>(nullptr, zA, ab + 2*64, F(19), F(20), F(21), F(22),
                                    zB, stats + 3*64, 1030, 32);
  k_bnfin<<<1, 64, 0, stream>>>(stats + 3*64, F(23), F(24), ab + 3*64, 1.f/(256.f*1032.f));

  k_lstm<<<256, 256, 0, stream>>>(zB, ab + 3*64,
                                  W1F, W2F, Uh1F, Ui1F, Ui2F, Uh2F,
                                  bias1, bias2,
                                  h1x, h2x, Axb, flags,
                                  fcw, fcb, outp);
}